// Round 4
// baseline (7850.007 us; speedup 1.0000x reference)
//
#include <hip/hip_runtime.h>
#include <stdint.h>

// ---------------------------------------------------------------------------
// complexLSTM: T=512, B=64, H=512, L=2   (persistent-kernel, bf16 MFMA)
//   Round 7: packed all-to-all barrier (single-hop) replacing master-mediated.
//   - arrival flags packed: arr[256] u32 = 1KB = 16 lines. Every block's
//     wave 0 polls ALL flags in ONE wavefront load (64 lanes x dwordx4,
//     sc0 sc1 bypass) -> one MALL RTT per poll sweep. __syncthreads releases.
//     Chain: drain -> arrival visible -> poll observe  (~3 hops, was ~6).
//   - no master block, no broadcast array, no cross-block jitter coupling.
//   - everything else from round 6: hist unique-address L2-cached panel
//     reads (batch-issued asm loads + single vmcnt(0)), coalesced
//     write-through h stores, lag-2 layer 1, outputs after arrival.
//   - fallback (ws too small for hist): ring + bypass loads (same barrier).
// ---------------------------------------------------------------------------

#define NPHASE 514

typedef __attribute__((ext_vector_type(8))) short short8;
typedef __attribute__((ext_vector_type(4))) float floatx4;
typedef float __attribute__((ext_vector_type(4))) floatv4;
typedef __attribute__((ext_vector_type(4))) unsigned int uintx4;

#define OFF_W    32768u                     // below: arr flags (1KB used)
#define SZ_W     (2u*4096u*2048u*2u)        // 33,554,432  packed bf16 weights
#define OFF_BIAS (OFF_W + SZ_W)
#define SZ_BIAS  (2u*4096u*4u)
#define OFF_H    (OFF_BIAS + SZ_BIAS)       // h hist [L][513][64][512] u32 (hi|hr)
#define SZ_H     (2u*513u*64u*512u*4u)      // 134,479,872
#define OFF_XBF  (OFF_H + SZ_H)             // optional bf16 x cache (planar)
#define SZ_XBF   (512u*64u*1024u*2u)        // 67,108,864
#define NEED_HIST ((size_t)OFF_XBF)
#define NEED_XBF  ((size_t)OFF_XBF + SZ_XBF)

__device__ __forceinline__ unsigned short f2bf(float f) {
  union { float f; uint32_t u; } v; v.f = f;
  uint32_t u = v.u;
  uint32_t r = (u + 0x7fffu + ((u >> 16) & 1u)) >> 16;   // RNE
  return (unsigned short)r;
}
__device__ __forceinline__ float sigm(float x)  { return 1.0f / (1.0f + __expf(-x)); }
__device__ __forceinline__ float tanhf_(float x){ return 1.0f - 2.0f / (1.0f + __expf(2.0f * x)); }

// Batch-issued 16B loads. Cached variant: L1/L2 allowed (hist mode — unique
// addresses make caching safe). Bypass variant: flags + ring fallback.
__device__ __forceinline__ uintx4 ld_cached_b128(const uint32_t* p) {
  uintx4 r;
  asm volatile("global_load_dwordx4 %0, %1, off" : "=v"(r) : "v"(p));
  return r;
}
__device__ __forceinline__ uintx4 ld_bypass_b128(const uint32_t* p) {
  uintx4 r;
  asm volatile("global_load_dwordx4 %0, %1, off sc0 sc1" : "=v"(r) : "v"(p));
  return r;
}
// Wait for all asm loads; sched_barrier stops MFMAs being hoisted above it.
__device__ __forceinline__ void wait_vm0() {
  asm volatile("s_waitcnt vmcnt(0)" ::: "memory");
  __builtin_amdgcn_sched_barrier(0);
}

// ---------------- prep kernels ----------------

// wp layout: [l][nb][kt(64)][nt(2)][lane(64)][j(8)] bf16 ; lane=(quad<<4)|mrow
// k-order (per layer):
//   l==0: k<1024 planar  [xr(512)|xi(512)] (matches xbf / fp32 cvt path)
//   l==1: k<1024 interleaved (d=k>>1, ri=k&1) — layer-0 h-hist IS the input
//   both: k>=1024 interleaved h (d=(k-1024)>>1, ri)
__global__ void pack_weights_k(const float* __restrict__ Wi_r, const float* __restrict__ Wi_i,
                               const float* __restrict__ Wh_r, const float* __restrict__ Wh_i,
                               unsigned short* __restrict__ wp) {
  uint32_t idx = blockIdx.x * 256u + threadIdx.x;   // < 16,777,216
  int j    = idx & 7;
  int lane = (idx >> 3) & 63;
  int nt   = (idx >> 9) & 1;
  int kt   = (idx >> 10) & 63;
  int nb   = (idx >> 16) & 127;
  int l    = idx >> 23;
  int mrow = lane & 15, quad = lane >> 4;
  int n_col = nt * 16 + mrow;
  int dd = n_col >> 3, g = n_col & 7;
  int jrow = (g & 3) * 512 + nb * 4 + dd;       // row in the (4H,H) weight
  int k = kt * 32 + quad * 8 + j;
  bool im = (g >= 4);
  size_t ro = ((size_t)l * 2048 + jrow) * 512;
  float v;
  if (k < 1024 && l == 0) {                      // planar x segment
    int seg = k >> 9, kk = k & 511;
    if (seg == 0) v = im ? Wi_i[ro + kk] :  Wi_r[ro + kk];
    else          v = im ? Wi_r[ro + kk] : -Wi_i[ro + kk];
  } else {                                       // interleaved segment
    int kk = k & 1023;
    int d = kk >> 1, ri = kk & 1;
    const float* Wr = (k < 1024) ? Wi_r : Wh_r;
    const float* Wm = (k < 1024) ? Wi_i : Wh_i;
    if (ri == 0) v = im ? Wm[ro + d] :  Wr[ro + d];
    else         v = im ? Wr[ro + d] : -Wm[ro + d];
  }
  wp[idx] = f2bf(v);
}

// bias packed as [l][nb][n_col(32)] fp32 (n_col = dd*8+g)
__global__ void pack_bias_k(const float* __restrict__ bi_r, const float* __restrict__ bi_i,
                            const float* __restrict__ bh_r, const float* __restrict__ bh_i,
                            float* __restrict__ bp) {
  uint32_t idx = blockIdx.x * 256u + threadIdx.x;   // < 8192
  int n_col = idx & 31, nb = (idx >> 5) & 127, l = idx >> 12;
  int dd = n_col >> 3, g = n_col & 7;
  int j = (g & 3) * 512 + nb * 4 + dd;
  float v = (g >= 4) ? (bi_i[l * 2048 + j] + bh_i[l * 2048 + j])
                     : (bi_r[l * 2048 + j] + bh_r[l * 2048 + j]);
  bp[idx] = v;
}

__global__ void init_state_k(const float* __restrict__ h0_r, const float* __restrict__ h0_i,
                             uint32_t* __restrict__ hist, uint32_t* __restrict__ bar,
                             int use_hist) {
  uint32_t idx = blockIdx.x * 256u + threadIdx.x;   // < 65536 = L*B*H
  if (idx < 8192) bar[idx] = 0;                     // flag lines (covers arr)
  int d = idx & 511, b = (idx >> 9) & 63, l = idx >> 15;
  size_t NS = use_hist ? 513 : 4;
  size_t slot;
  if (use_hist) slot = 0;                           // slot 0 = initial state
  else          slot = (2 * l + 3) & 3;             // ring mode (round-4)
  uint32_t* row = hist + ((size_t)l * NS + slot) * 32768 + (size_t)b * 512;
  row[d] = ((uint32_t)f2bf(h0_i[idx]) << 16) | (uint32_t)f2bf(h0_r[idx]);
}

__global__ void convert_x_k(const float* __restrict__ xr, const float* __restrict__ xi,
                            unsigned short* __restrict__ xbf) {
  uint32_t idx = blockIdx.x * 256u + threadIdx.x;   // < 33,554,432 = T*B*1024
  int k = idx & 1023;
  uint32_t row = idx >> 10;                         // t*64 + b
  float v = (k < 512) ? xr[(size_t)row * 512 + k] : xi[(size_t)row * 512 + (k - 512)];
  xbf[idx] = f2bf(v);
}

// ---------------- main persistent kernel ----------------

__global__ __launch_bounds__(256, 1) void lstm_persist_k(
    const float* __restrict__ xr, const float* __restrict__ xi,
    const float* __restrict__ c0_r, const float* __restrict__ c0_i,
    const unsigned short* __restrict__ wp, const float* __restrict__ bp,
    uint32_t* __restrict__ hist, const unsigned short* __restrict__ xbf,
    float* __restrict__ out, uint32_t* arr, int use_xbf, int use_hist)
{
  __shared__ short8 Wb[8192];                  // 131,072 B : [kt][nt][lane] fragments
  __shared__ float Glds[64 * 33];              //   8,448 B
  __shared__ float bias_s[32];

  const int l   = blockIdx.x >> 7;     // layer
  const int nb  = blockIdx.x & 127;    // gate-col chunk [32nb, 32nb+32)
  const int bid = blockIdx.x;
  const int tid = threadIdx.x;

  // stage this block's weight slice into LDS: straight 131,072B contiguous copy
  {
    const short8* src = (const short8*)(wp + (((size_t)l * 128 + nb) << 16));
    #pragma unroll
    for (int i = 0; i < 32; ++i) Wb[i * 256 + tid] = src[i * 256 + tid];
    if (tid < 32) bias_s[tid] = bp[(l * 128 + nb) * 32 + tid];
  }

  // elementwise ownership: 4 consecutive lanes own the 4 dds of one batch
  // -> per-thread 4B stores coalesce into 16B segments.
  const int b_e = tid >> 2, dd_e = tid & 3;
  const int d_e = nb * 4 + dd_e;
  float cr = c0_r[(l * 64 + b_e) * 512 + d_e];
  float ci = c0_i[(l * 64 + b_e) * 512 + d_e];
  __syncthreads();

  // wave w = m-tile w: batches b = w*16 + mrow ; computes both n-tiles
  const int wv = tid >> 6, lane = tid & 63;
  const int quad = lane >> 4, mrow = lane & 15;
  const int bm = wv * 16 + mrow;                  // this lane's A row (batch)
  const bool cvt_path = (l == 0) && (!use_xbf);

  const size_t NS = use_hist ? 513 : 4;
  uint32_t* hbase_l = hist + (size_t)l * NS * 32768;   // own layer's history
  uint32_t* hbase_0 = hist;                            // layer-0 history
  auto sidx = [&](int s) -> size_t { return use_hist ? (size_t)s : (size_t)(s & 3); };

  for (int p = 0; p < NPHASE; ++p) {
    const int t = p - 2 * l;                      // layer l at lag 2l
    const bool active = (t >= 0) && (t < 512);
    floatx4 acc0 = {0.f, 0.f, 0.f, 0.f}, acc1 = {0.f, 0.f, 0.f, 0.f};

    // ---- A: x-half GEMM (independent of the pending barrier) ----
    if (active) {
      if (l == 0) {
        if (cvt_path) {
          const size_t xtb = ((size_t)t * 64 + bm) * 512 + quad * 8;
          #pragma unroll 8
          for (int kt = 0; kt < 32; ++kt) {
            const float* xb = ((kt < 16) ? xr : xi) + xtb + (kt & 15) * 32;
            floatv4 f0 = *(const floatv4*)xb;
            floatv4 f1 = *(const floatv4*)(xb + 4);
            short8 a;
            #pragma unroll
            for (int jj = 0; jj < 4; ++jj) { a[jj] = (short)f2bf(f0[jj]); a[jj+4] = (short)f2bf(f1[jj]); }
            short8 bf0 = Wb[(kt * 2 + 0) * 64 + lane];
            short8 bf1 = Wb[(kt * 2 + 1) * 64 + lane];
            acc0 = __builtin_amdgcn_mfma_f32_16x16x32_bf16(a, bf0, acc0, 0, 0, 0);
            acc1 = __builtin_amdgcn_mfma_f32_16x16x32_bf16(a, bf1, acc1, 0, 0, 0);
          }
        } else {
          const unsigned short* xb = xbf + ((size_t)t * 64 + bm) * 1024 + quad * 8;
          #pragma unroll 8
          for (int kt = 0; kt < 32; ++kt) {
            short8 a = *(const short8*)(xb + kt * 32);
            short8 bf0 = Wb[(kt * 2 + 0) * 64 + lane];
            short8 bf1 = Wb[(kt * 2 + 1) * 64 + lane];
            acc0 = __builtin_amdgcn_mfma_f32_16x16x32_bf16(a, bf0, acc0, 0, 0, 0);
            acc1 = __builtin_amdgcn_mfma_f32_16x16x32_bf16(a, bf1, acc1, 0, 0, 0);
          }
        }
      } else {
        // layer-1 input = layer-0 h[t] (slot t+1 = p-1), written phase p-2,
        // visibility via barrier gen p-1 (observed last iteration).
        const uint32_t* xb = hbase_0 + sidx(p - 1) * 32768 + (size_t)bm * 512 + quad * 4;
        uintx4 xp[32];
        if (use_hist) {
          #pragma unroll
          for (int i = 0; i < 32; ++i) xp[i] = ld_cached_b128(xb + i * 16);
        } else {
          #pragma unroll
          for (int i = 0; i < 32; ++i) xp[i] = ld_bypass_b128(xb + i * 16);
        }
        wait_vm0();
        #pragma unroll
        for (int i = 0; i < 32; ++i) {
          short8 a = __builtin_bit_cast(short8, xp[i]);
          short8 bf0 = Wb[(i * 2 + 0) * 64 + lane];
          short8 bf1 = Wb[(i * 2 + 1) * 64 + lane];
          acc0 = __builtin_amdgcn_mfma_f32_16x16x32_bf16(a, bf0, acc0, 0, 0, 0);
          acc1 = __builtin_amdgcn_mfma_f32_16x16x32_bf16(a, bf1, acc1, 0, 0, 0);
        }
      }
    }

    // ---- B: packed all-to-all barrier: wait until all flags >= p ----
    // Wave 0 reads ALL 256 flags in one wavefront load (64 lanes x dwordx4,
    // bypass) -> one MALL RTT per sweep. __syncthreads releases waves 1-3.
    {
      const uint32_t g = (uint32_t)p;
      if (wv == 0) {
        const uint32_t* ap = arr + lane * 4;
        long budget = (1L << 22);
        for (;;) {
          uintx4 v = ld_bypass_b128(ap);
          wait_vm0();
          bool ok = (v.x >= g) & (v.y >= g) & (v.z >= g) & (v.w >= g);
          if (__all(ok)) break;
          if (--budget <= 0) break;
        }
      }
      __syncthreads();
      // NO cache fence: hist addresses are unique per timestep; write-through
      // stores populated the coherence point; cached reads can't be stale.
    }

    // ---- C: h-half GEMM (own layer state h[t-1], slot t; written ph p-1) ----
    if (active) {
      const uint32_t* hb = hbase_l + sidx(t) * 32768 + (size_t)bm * 512 + quad * 4;
      uintx4 hp[32];
      if (use_hist) {
        #pragma unroll
        for (int i = 0; i < 32; ++i) hp[i] = ld_cached_b128(hb + i * 16);
      } else {
        #pragma unroll
        for (int i = 0; i < 32; ++i) hp[i] = ld_bypass_b128(hb + i * 16);
      }
      wait_vm0();
      #pragma unroll
      for (int i = 0; i < 32; ++i) {
        short8 a = __builtin_bit_cast(short8, hp[i]);
        short8 bf0 = Wb[((32 + i) * 2 + 0) * 64 + lane];
        short8 bf1 = Wb[((32 + i) * 2 + 1) * 64 + lane];
        acc0 = __builtin_amdgcn_mfma_f32_16x16x32_bf16(a, bf0, acc0, 0, 0, 0);
        acc1 = __builtin_amdgcn_mfma_f32_16x16x32_bf16(a, bf1, acc1, 0, 0, 0);
      }
      // D layout: col = lane&15, row(within m-tile) = quad*4 + r  (m89/m91)
      const float bb0 = bias_s[mrow], bb1 = bias_s[16 + mrow];
      const int rowb = wv * 16 + quad * 4;
      #pragma unroll
      for (int r = 0; r < 4; ++r) {
        Glds[(rowb + r) * 33 + mrow]      = acc0[r] + bb0;
        Glds[(rowb + r) * 33 + 16 + mrow] = acc1[r] + bb1;
      }
    }
    __syncthreads();

    // ---- D: nonlinearity + write-through h store (coalesced 4-lane groups) --
    float h_r = 0.f, h_i = 0.f;
    if (active) {
      const float* gp = &Glds[b_e * 33 + dd_e * 8];
      float i_r = sigm(gp[0]), f_r = sigm(gp[1]), gc_r = tanhf_(gp[2]), o_r = sigm(gp[3]);
      float i_i = sigm(gp[4]), f_i = sigm(gp[5]), gc_i = tanhf_(gp[6]), o_i = sigm(gp[7]);
      float cr2 = f_r * cr - f_i * ci + i_r * gc_r - i_i * gc_i;
      float ci2 = f_r * ci + f_i * cr + i_r * gc_i + i_i * gc_r;
      cr = cr2; ci = ci2;
      float t_r = tanhf_(cr), t_i = tanhf_(ci);
      h_r = o_r * t_r - o_i * t_i;
      h_i = o_r * t_i + o_i * t_r;
      uint32_t hpk = ((uint32_t)f2bf(h_i) << 16) | (uint32_t)f2bf(h_r);
      uint32_t* hw = hbase_l + sidx(t + 1) * 32768 + (size_t)b_e * 512 + d_e;
      __hip_atomic_store(hw, hpk, __ATOMIC_RELAXED, __HIP_MEMORY_SCOPE_AGENT);
    }
    // __syncthreads emits s_waitcnt vmcnt(0): all write-through h stores are
    // acked at the coherence point before the arrival store issues (release).
    __syncthreads();
    if (tid == 0)
      __hip_atomic_store(&arr[bid], (uint32_t)(p + 1),
                         __ATOMIC_RELAXED, __HIP_MEMORY_SCOPE_AGENT);

    // ---- E: sequence/final outputs (plain cached; gate nothing -> after
    //        arrival, overlapping the next phase's x-half) ----
    if (active) {
      if (l == 1) {
        size_t o = ((size_t)t * 64 + b_e) * 512 + d_e;
        out[o]             = h_r;
        out[16777216u + o] = h_i;
      }
      if (t == 511) {
        size_t o = 33554432u + ((size_t)l * 64 + b_e) * 512 + d_e;
        out[o]          = h_r;
        out[o + 65536u] = h_i;
      }
    }
  }
}

// ---------------- host ----------------

extern "C" void kernel_launch(void* const* d_in, const int* in_sizes, int n_in,
                              void* d_out, int out_size, void* d_ws, size_t ws_size,
                              hipStream_t stream) {
  const float* seq_r = (const float*)d_in[0];
  const float* seq_i = (const float*)d_in[1];
  const float* h0_r  = (const float*)d_in[2];
  const float* h0_i  = (const float*)d_in[3];
  const float* c0_r  = (const float*)d_in[4];
  const float* c0_i  = (const float*)d_in[5];
  const float* Wi_r  = (const float*)d_in[6];
  const float* Wi_i  = (const float*)d_in[7];
  const float* Wh_r  = (const float*)d_in[8];
  const float* Wh_i  = (const float*)d_in[9];
  const float* bi_r  = (const float*)d_in[10];
  const float* bi_i  = (const float*)d_in[11];
  const float* bh_r  = (const float*)d_in[12];
  const float* bh_i  = (const float*)d_in[13];

  char* ws = (char*)d_ws;
  uint32_t* arr    = (uint32_t*)ws;                 // 256 packed u32 flags (1KB)
  unsigned short* wp   = (unsigned short*)(ws + OFF_W);
  float*          bias = (float*)(ws + OFF_BIAS);
  uint32_t*       hist = (uint32_t*)(ws + OFF_H);
  unsigned short* xbf  = (unsigned short*)(ws + OFF_XBF);
  const int use_hist = (ws_size >= NEED_HIST) ? 1 : 0;
  const int use_xbf  = (ws_size >= NEED_XBF) ? 1 : 0;

  pack_weights_k<<<65536, 256, 0, stream>>>(Wi_r, Wi_i, Wh_r, Wh_i, wp);
  pack_bias_k<<<32, 256, 0, stream>>>(bi_r, bi_i, bh_r, bh_i, bias);
  init_state_k<<<256, 256, 0, stream>>>(h0_r, h0_i, hist, arr, use_hist);
  if (use_xbf) convert_x_k<<<131072, 256, 0, stream>>>(seq_r, seq_i, xbf);

  lstm_persist_k<<<256, 256, 0, stream>>>(seq_r, seq_i, c0_r, c0_i, wp, bias,
                                          hist, xbf, (float*)d_out, arr,
                                          use_xbf, use_hist);
}

// Round 5
// 7383.075 us; speedup vs baseline: 1.0632x; 1.0632x over previous
//
#include <hip/hip_runtime.h>
#include <stdint.h>

// ---------------------------------------------------------------------------
// complexLSTM: T=512, B=64, H=512, L=2   (persistent-kernel, bf16 MFMA)
//   Round 8: R1 protocol + REGISTER-RESIDENT h-half weights.
//   - h-half B-fragments (64 x short8 = 256 regs, identical for all waves)
//     are loaded ONCE into registers at init. The post-barrier critical
//     section (h-half GEMM) does ZERO LDS reads: 32 batched bypass loads ->
//     vmcnt(0) -> 64 register-only MFMAs. At 1 block/CU, 512 unified
//     VGPR+AGPR per wave make this fit (~430 live peak).
//   - LDS holds only the x-half weights (65 KB), consumed in section A
//     which overlaps the barrier wait.
//   - everything else = R1 (best measured, 6.75 ms): 4-slot ring (warm
//     addresses), bypass panel loads, write-through per-thread h stores,
//     master-mediated barrier (private arrival + broadcast lines),
//     lag-2 layer 1, seq/final outputs after the arrival post.
// ---------------------------------------------------------------------------

#define NPHASE 514

typedef __attribute__((ext_vector_type(8))) short short8;
typedef __attribute__((ext_vector_type(4))) float floatx4;
typedef float __attribute__((ext_vector_type(4))) floatv4;
typedef __attribute__((ext_vector_type(4))) unsigned int uintx4;

#define OFF_W    32768u                     // below: arr[256] + gen_bc[256] lines
#define SZ_W     (2u*4096u*2048u*2u)        // 33,554,432  packed bf16 weights
#define OFF_BIAS (OFF_W + SZ_W)
#define SZ_BIAS  (2u*4096u*4u)
#define OFF_H    (OFF_BIAS + SZ_BIAS)       // h ring [L][4][64][512] u32 (hi|hr)
#define SZ_H     (2u*4u*64u*512u*4u)        // 1,048,576
#define OFF_XBF  (OFF_H + SZ_H)             // optional bf16 x cache (planar)
#define SZ_XBF   (512u*64u*1024u*2u)        // 67,108,864
#define NEED_XBF ((size_t)OFF_XBF + SZ_XBF)

__device__ __forceinline__ unsigned short f2bf(float f) {
  union { float f; uint32_t u; } v; v.f = f;
  uint32_t u = v.u;
  uint32_t r = (u + 0x7fffu + ((u >> 16) & 1u)) >> 16;   // RNE
  return (unsigned short)r;
}
__device__ __forceinline__ float sigm(float x)  { return 1.0f / (1.0f + __expf(-x)); }
__device__ __forceinline__ float tanhf_(float x){ return 1.0f - 2.0f / (1.0f + __expf(2.0f * x)); }

// L2-bypassing 16B load (system-scope): always reads the coherence point.
__device__ __forceinline__ uintx4 ld_bypass_b128(const uint32_t* p) {
  uintx4 r;
  asm volatile("global_load_dwordx4 %0, %1, off sc0 sc1" : "=v"(r) : "v"(p));
  return r;
}
// Wait for all asm loads; sched_barrier stops MFMAs being hoisted above it.
__device__ __forceinline__ void wait_vm0() {
  asm volatile("s_waitcnt vmcnt(0)" ::: "memory");
  __builtin_amdgcn_sched_barrier(0);
}

// ---------------- prep kernels ----------------

// wp layout: [l][nb][kt(64)][nt(2)][lane(64)][j(8)] bf16 ; lane=(quad<<4)|mrow
// k-order (per layer):
//   l==0: k<1024 planar  [xr(512)|xi(512)] (matches xbf / fp32 cvt path)
//   l==1: k<1024 interleaved (d=k>>1, ri=k&1) — layer-0 h-ring IS the input
//   both: k>=1024 interleaved h (d=(k-1024)>>1, ri)
__global__ void pack_weights_k(const float* __restrict__ Wi_r, const float* __restrict__ Wi_i,
                               const float* __restrict__ Wh_r, const float* __restrict__ Wh_i,
                               unsigned short* __restrict__ wp) {
  uint32_t idx = blockIdx.x * 256u + threadIdx.x;   // < 16,777,216
  int j    = idx & 7;
  int lane = (idx >> 3) & 63;
  int nt   = (idx >> 9) & 1;
  int kt   = (idx >> 10) & 63;
  int nb   = (idx >> 16) & 127;
  int l    = idx >> 23;
  int mrow = lane & 15, quad = lane >> 4;
  int n_col = nt * 16 + mrow;
  int dd = n_col >> 3, g = n_col & 7;
  int jrow = (g & 3) * 512 + nb * 4 + dd;       // row in the (4H,H) weight
  int k = kt * 32 + quad * 8 + j;
  bool im = (g >= 4);
  size_t ro = ((size_t)l * 2048 + jrow) * 512;
  float v;
  if (k < 1024 && l == 0) {                      // planar x segment
    int seg = k >> 9, kk = k & 511;
    if (seg == 0) v = im ? Wi_i[ro + kk] :  Wi_r[ro + kk];
    else          v = im ? Wi_r[ro + kk] : -Wi_i[ro + kk];
  } else {                                       // interleaved segment
    int kk = k & 1023;
    int d = kk >> 1, ri = kk & 1;
    const float* Wr = (k < 1024) ? Wi_r : Wh_r;
    const float* Wm = (k < 1024) ? Wi_i : Wh_i;
    if (ri == 0) v = im ? Wm[ro + d] :  Wr[ro + d];
    else         v = im ? Wr[ro + d] : -Wm[ro + d];
  }
  wp[idx] = f2bf(v);
}

// bias packed as [l][nb][n_col(32)] fp32 (n_col = dd*8+g)
__global__ void pack_bias_k(const float* __restrict__ bi_r, const float* __restrict__ bi_i,
                            const float* __restrict__ bh_r, const float* __restrict__ bh_i,
                            float* __restrict__ bp) {
  uint32_t idx = blockIdx.x * 256u + threadIdx.x;   // < 8192
  int n_col = idx & 31, nb = (idx >> 5) & 127, l = idx >> 12;
  int dd = n_col >> 3, g = n_col & 7;
  int j = (g & 3) * 512 + nb * 4 + dd;
  float v = (g >= 4) ? (bi_i[l * 2048 + j] + bh_i[l * 2048 + j])
                     : (bi_r[l * 2048 + j] + bh_r[l * 2048 + j]);
  bp[idx] = v;
}

__global__ void init_state_k(const float* __restrict__ h0_r, const float* __restrict__ h0_i,
                             uint32_t* __restrict__ hring32, uint32_t* __restrict__ bar) {
  uint32_t idx = blockIdx.x * 256u + threadIdx.x;   // < 65536 = L*B*H
  if (idx < 8192) bar[idx] = 0;                     // arr + gen_bc lines (32KB)
  int d = idx & 511, b = (idx >> 9) & 63, l = idx >> 15;
  // C at phase p reads slot t&3 = state h[t-1]; initial state h[-1] -> slot 0
  uint32_t* row = hring32 + ((size_t)l * 4) * 32768 + (size_t)b * 512;
  row[d] = ((uint32_t)f2bf(h0_i[idx]) << 16) | (uint32_t)f2bf(h0_r[idx]);
}

__global__ void convert_x_k(const float* __restrict__ xr, const float* __restrict__ xi,
                            unsigned short* __restrict__ xbf) {
  uint32_t idx = blockIdx.x * 256u + threadIdx.x;   // < 33,554,432 = T*B*1024
  int k = idx & 1023;
  uint32_t row = idx >> 10;                         // t*64 + b
  float v = (k < 512) ? xr[(size_t)row * 512 + k] : xi[(size_t)row * 512 + (k - 512)];
  xbf[idx] = f2bf(v);
}

// ---------------- main persistent kernel ----------------

__global__ __launch_bounds__(256, 1) void lstm_persist_k(
    const float* __restrict__ xr, const float* __restrict__ xi,
    const float* __restrict__ c0_r, const float* __restrict__ c0_i,
    const unsigned short* __restrict__ wp, const float* __restrict__ bp,
    uint32_t* __restrict__ hring32, const unsigned short* __restrict__ xbf,
    float* __restrict__ out, uint32_t* arr, uint32_t* gen_bc, int use_xbf)
{
  __shared__ short8 Wb[4096];                  // 65,536 B : x-half [kt<32][nt][lane]
  __shared__ float Glds[64 * 33];              //   8,448 B
  __shared__ float bias_s[32];

  const int l   = blockIdx.x >> 7;     // layer
  const int nb  = blockIdx.x & 127;    // gate-col chunk [32nb, 32nb+32)
  const int bid = blockIdx.x;
  const int tid = threadIdx.x;
  const int wv = tid >> 6, lane = tid & 63;
  const int quad = lane >> 4, mrow = lane & 15;
  const int bm = wv * 16 + mrow;                  // this lane's A row (batch)

  // stage x-half weight slice into LDS (first 65,536 B of the block's slice)
  {
    const short8* src = (const short8*)(wp + (((size_t)l * 128 + nb) << 16));
    #pragma unroll
    for (int i = 0; i < 16; ++i) Wb[i * 256 + tid] = src[i * 256 + tid];
    if (tid < 32) bias_s[tid] = bp[(l * 128 + nb) * 32 + tid];
  }

  // REGISTER-RESIDENT h-half weights: 64 x short8 = 256 regs per lane.
  // Identical across waves (B-frags depend on (kt,nt,lane) only).
  short8 wh[64];
  {
    const short8* wsrc = (const short8*)wp + ((size_t)(l * 128 + nb) * 8192);
    #pragma unroll
    for (int m = 0; m < 64; ++m) wh[m] = wsrc[(64 + m) * 64 + lane];
  }

  // elementwise ownership + register-resident cell state (R1 mapping)
  const int b_e = tid & 63, dd_e = tid >> 6;
  const int d_e = nb * 4 + dd_e;
  float cr = c0_r[(l * 64 + b_e) * 512 + d_e];
  float ci = c0_i[(l * 64 + b_e) * 512 + d_e];
  __syncthreads();

  const bool cvt_path = (l == 0) && (!use_xbf);
  uint32_t* hbase_l = hring32 + (size_t)l * 4 * 32768;   // own layer's ring

  for (int p = 0; p < NPHASE; ++p) {
    const int t = p - 2 * l;                      // layer l at lag 2l
    const bool active = (t >= 0) && (t < 512);
    floatx4 acc0 = {0.f, 0.f, 0.f, 0.f}, acc1 = {0.f, 0.f, 0.f, 0.f};

    // ---- A: x-half GEMM (independent of the pending barrier; LDS B-frags) --
    if (active) {
      if (l == 0) {
        if (cvt_path) {
          const size_t xtb = ((size_t)t * 64 + bm) * 512 + quad * 8;
          #pragma unroll 8
          for (int kt = 0; kt < 32; ++kt) {
            const float* xb = ((kt < 16) ? xr : xi) + xtb + (kt & 15) * 32;
            floatv4 f0 = *(const floatv4*)xb;
            floatv4 f1 = *(const floatv4*)(xb + 4);
            short8 a;
            #pragma unroll
            for (int jj = 0; jj < 4; ++jj) { a[jj] = (short)f2bf(f0[jj]); a[jj+4] = (short)f2bf(f1[jj]); }
            short8 bf0 = Wb[(kt * 2 + 0) * 64 + lane];
            short8 bf1 = Wb[(kt * 2 + 1) * 64 + lane];
            acc0 = __builtin_amdgcn_mfma_f32_16x16x32_bf16(a, bf0, acc0, 0, 0, 0);
            acc1 = __builtin_amdgcn_mfma_f32_16x16x32_bf16(a, bf1, acc1, 0, 0, 0);
          }
        } else {
          const unsigned short* xb = xbf + ((size_t)t * 64 + bm) * 1024 + quad * 8;
          #pragma unroll 8
          for (int kt = 0; kt < 32; ++kt) {
            short8 a = *(const short8*)(xb + kt * 32);
            short8 bf0 = Wb[(kt * 2 + 0) * 64 + lane];
            short8 bf1 = Wb[(kt * 2 + 1) * 64 + lane];
            acc0 = __builtin_amdgcn_mfma_f32_16x16x32_bf16(a, bf0, acc0, 0, 0, 0);
            acc1 = __builtin_amdgcn_mfma_f32_16x16x32_bf16(a, bf1, acc1, 0, 0, 0);
          }
        }
      } else {
        // layer-1 input = layer-0 h[t] (slot (p-1)&3), written phase p-2,
        // visibility via barrier gen p-1. Two 16-batches to cap reg pressure.
        const uint32_t* xb = hring32 + ((size_t)((p - 1) & 3) * 64 + bm) * 512 + quad * 4;
        #pragma unroll
        for (int half = 0; half < 2; ++half) {
          uintx4 xp[16];
          #pragma unroll
          for (int i = 0; i < 16; ++i) xp[i] = ld_bypass_b128(xb + (half * 16 + i) * 16);
          wait_vm0();
          #pragma unroll
          for (int i = 0; i < 16; ++i) {
            const int kt = half * 16 + i;
            short8 a = __builtin_bit_cast(short8, xp[i]);
            short8 bf0 = Wb[(kt * 2 + 0) * 64 + lane];
            short8 bf1 = Wb[(kt * 2 + 1) * 64 + lane];
            acc0 = __builtin_amdgcn_mfma_f32_16x16x32_bf16(a, bf0, acc0, 0, 0, 0);
            acc1 = __builtin_amdgcn_mfma_f32_16x16x32_bf16(a, bf1, acc1, 0, 0, 0);
          }
        }
      }
    }

    // ---- B: master-mediated barrier (R1): wait for generation p ----
    {
      const uint32_t g = (uint32_t)p;
      long budget = (1L << 22);
      if (bid == 0) {
        if (tid > 0) {      // thread i polls block i's private arrival line
          while (__hip_atomic_load(&arr[tid * 16], __ATOMIC_RELAXED, __HIP_MEMORY_SCOPE_AGENT) < g) {
            if (--budget <= 0) break;
          }
        }
        __syncthreads();    // all arrivals observed
        __hip_atomic_store(&gen_bc[tid * 16], g, __ATOMIC_RELAXED, __HIP_MEMORY_SCOPE_AGENT);
      } else {
        if (tid < 64) {     // wave 0 polls; __syncthreads releases waves 1-3
          while (__hip_atomic_load(&gen_bc[bid * 16], __ATOMIC_RELAXED, __HIP_MEMORY_SCOPE_AGENT) < g) {
            if (--budget <= 0) break;
          }
        }
        __syncthreads();
      }
      // NO cache fence: ring reads below bypass L1/L2 (sc0 sc1).
    }

    // ---- C: h-half GEMM — critical section, ZERO LDS reads ----
    if (active) {
      const uint32_t* hb = hbase_l + ((size_t)(t & 3) * 64 + bm) * 512 + quad * 4;
      uintx4 hp[32];
      #pragma unroll
      for (int i = 0; i < 32; ++i) hp[i] = ld_bypass_b128(hb + i * 16);
      wait_vm0();
      #pragma unroll
      for (int i = 0; i < 32; ++i) {
        short8 a = __builtin_bit_cast(short8, hp[i]);
        acc0 = __builtin_amdgcn_mfma_f32_16x16x32_bf16(a, wh[2 * i],     acc0, 0, 0, 0);
        acc1 = __builtin_amdgcn_mfma_f32_16x16x32_bf16(a, wh[2 * i + 1], acc1, 0, 0, 0);
      }
      // D layout: col = lane&15, row(within m-tile) = quad*4 + r  (m89/m91)
      const float bb0 = bias_s[mrow], bb1 = bias_s[16 + mrow];
      const int rowb = wv * 16 + quad * 4;
      #pragma unroll
      for (int r = 0; r < 4; ++r) {
        Glds[(rowb + r) * 33 + mrow]      = acc0[r] + bb0;
        Glds[(rowb + r) * 33 + 16 + mrow] = acc1[r] + bb1;
      }
    }
    __syncthreads();

    // ---- D: nonlinearity + write-through h store ----
    float h_r = 0.f, h_i = 0.f;
    if (active) {
      const float* gp = &Glds[b_e * 33 + dd_e * 8];
      float i_r = sigm(gp[0]), f_r = sigm(gp[1]), gc_r = tanhf_(gp[2]), o_r = sigm(gp[3]);
      float i_i = sigm(gp[4]), f_i = sigm(gp[5]), gc_i = tanhf_(gp[6]), o_i = sigm(gp[7]);
      float cr2 = f_r * cr - f_i * ci + i_r * gc_r - i_i * gc_i;
      float ci2 = f_r * ci + f_i * cr + i_r * gc_i + i_i * gc_r;
      cr = cr2; ci = ci2;
      float t_r = tanhf_(cr), t_i = tanhf_(ci);
      h_r = o_r * t_r - o_i * t_i;
      h_i = o_r * t_i + o_i * t_r;
      uint32_t hpk = ((uint32_t)f2bf(h_i) << 16) | (uint32_t)f2bf(h_r);
      uint32_t* hw = hbase_l + ((size_t)((t + 1) & 3) * 64 + b_e) * 512 + d_e;
      __hip_atomic_store(hw, hpk, __ATOMIC_RELAXED, __HIP_MEMORY_SCOPE_AGENT);
    }
    // __syncthreads emits s_waitcnt vmcnt(0): all write-through h stores are
    // acked at the coherence point before the arrival store issues (release).
    __syncthreads();
    if (bid != 0 && tid == 0)
      __hip_atomic_store(&arr[bid * 16], (uint32_t)(p + 1),
                         __ATOMIC_RELAXED, __HIP_MEMORY_SCOPE_AGENT);

    // ---- E: sequence/final outputs (plain cached; after arrival post) ----
    if (active) {
      if (l == 1) {
        size_t o = ((size_t)t * 64 + b_e) * 512 + d_e;
        out[o]             = h_r;
        out[16777216u + o] = h_i;
      }
      if (t == 511) {
        size_t o = 33554432u + ((size_t)l * 64 + b_e) * 512 + d_e;
        out[o]          = h_r;
        out[o + 65536u] = h_i;
      }
    }
  }
}

// ---------------- host ----------------

extern "C" void kernel_launch(void* const* d_in, const int* in_sizes, int n_in,
                              void* d_out, int out_size, void* d_ws, size_t ws_size,
                              hipStream_t stream) {
  const float* seq_r = (const float*)d_in[0];
  const float* seq_i = (const float*)d_in[1];
  const float* h0_r  = (const float*)d_in[2];
  const float* h0_i  = (const float*)d_in[3];
  const float* c0_r  = (const float*)d_in[4];
  const float* c0_i  = (const float*)d_in[5];
  const float* Wi_r  = (const float*)d_in[6];
  const float* Wi_i  = (const float*)d_in[7];
  const float* Wh_r  = (const float*)d_in[8];
  const float* Wh_i  = (const float*)d_in[9];
  const float* bi_r  = (const float*)d_in[10];
  const float* bi_i  = (const float*)d_in[11];
  const float* bh_r  = (const float*)d_in[12];
  const float* bh_i  = (const float*)d_in[13];

  char* ws = (char*)d_ws;
  uint32_t* arr    = (uint32_t*)ws;                 // 256 lines, 64B stride
  uint32_t* gen_bc = (uint32_t*)(ws + 16384);       // 256 lines, 64B stride
  unsigned short* wp   = (unsigned short*)(ws + OFF_W);
  float*          bias = (float*)(ws + OFF_BIAS);
  uint32_t*       hrg  = (uint32_t*)(ws + OFF_H);
  unsigned short* xbf  = (unsigned short*)(ws + OFF_XBF);
  const int use_xbf = (ws_size >= NEED_XBF) ? 1 : 0;

  pack_weights_k<<<65536, 256, 0, stream>>>(Wi_r, Wi_i, Wh_r, Wh_i, wp);
  pack_bias_k<<<32, 256, 0, stream>>>(bi_r, bi_i, bh_r, bh_i, bias);
  init_state_k<<<256, 256, 0, stream>>>(h0_r, h0_i, hrg, arr);
  if (use_xbf) convert_x_k<<<131072, 256, 0, stream>>>(seq_r, seq_i, xbf);

  lstm_persist_k<<<256, 256, 0, stream>>>(seq_r, seq_i, c0_r, c0_i, wp, bias,
                                          hrg, xbf, (float*)d_out, arr, gen_bc, use_xbf);
}

// Round 6
// 6537.469 us; speedup vs baseline: 1.2008x; 1.1293x over previous
//
#include <hip/hip_runtime.h>
#include <stdint.h>

// ---------------------------------------------------------------------------
// complexLSTM: T=512, B=64, H=512, L=2   (persistent-kernel, bf16 MFMA)
//   Round 9: R1 structure + PRODUCER FAN-OUT barrier (no master, no hot lines).
//   - flags[c][j] (256x256 u32): consumer c's PRIVATE poll array. Producer
//     block j posts gen to flags[c][j] for all c — one store per thread
//     (thread tid -> flags[tid][bid]). Each 64B line: 16 writers (distinct
//     u32s), ONE reader. Consumer wave 0 sweeps its own 1KB array in a
//     single 64-lane dwordx4 bypass load + __all check.
//     Chain: h-drain -> fan-out store -> observe  (3 hops; R1 had 5).
//   - h stores: R3 remap (b_e=tid>>2, dd_e=tid&3) -> 16B-coalesced
//     write-through (WRITE_SIZE 2.1 -> 0.53 GB), no LDS repack.
//   - everything else = R1 (best measured): 4-slot ring, bypass panel loads
//     batch-issued + single vmcnt(0), full weights in LDS (128KB), lag-2
//     layer 1, x-half GEMM before the barrier poll, outputs after arrival.
// ---------------------------------------------------------------------------

#define NPHASE 514

typedef __attribute__((ext_vector_type(8))) short short8;
typedef __attribute__((ext_vector_type(4))) float floatx4;
typedef float __attribute__((ext_vector_type(4))) floatv4;
typedef __attribute__((ext_vector_type(4))) unsigned int uintx4;

#define OFF_W    262144u                    // below: flags[256][256] u32
#define SZ_W     (2u*4096u*2048u*2u)        // 33,554,432  packed bf16 weights
#define OFF_BIAS (OFF_W + SZ_W)
#define SZ_BIAS  (2u*4096u*4u)
#define OFF_H    (OFF_BIAS + SZ_BIAS)       // h rings [L][4][64][512] u32 (hi|hr)
#define SZ_H     (2u*4u*64u*512u*4u)        // 1,048,576
#define OFF_XBF  (OFF_H + SZ_H)             // optional bf16 x cache (planar)
#define SZ_XBF   (512u*64u*1024u*2u)        // 67,108,864
#define NEED_XBF ((size_t)OFF_XBF + SZ_XBF)

__device__ __forceinline__ unsigned short f2bf(float f) {
  union { float f; uint32_t u; } v; v.f = f;
  uint32_t u = v.u;
  uint32_t r = (u + 0x7fffu + ((u >> 16) & 1u)) >> 16;   // RNE
  return (unsigned short)r;
}
__device__ __forceinline__ float sigm(float x)  { return 1.0f / (1.0f + __expf(-x)); }
__device__ __forceinline__ float tanhf_(float x){ return 1.0f - 2.0f / (1.0f + __expf(2.0f * x)); }

// L2-bypassing 16B load (system-scope): always reads the coherence point.
__device__ __forceinline__ uintx4 ld_bypass_b128(const uint32_t* p) {
  uintx4 r;
  asm volatile("global_load_dwordx4 %0, %1, off sc0 sc1" : "=v"(r) : "v"(p));
  return r;
}
// Wait for all asm loads; sched_barrier stops MFMAs being hoisted above it.
__device__ __forceinline__ void wait_vm0() {
  asm volatile("s_waitcnt vmcnt(0)" ::: "memory");
  __builtin_amdgcn_sched_barrier(0);
}

// ---------------- prep kernels ----------------

// wp layout: [l][nb][kt(64)][nt(2)][lane(64)][j(8)] bf16 ; lane=(quad<<4)|mrow
// k-order (per layer):
//   l==0: k<1024 planar  [xr(512)|xi(512)] (matches xbf / fp32 cvt path)
//   l==1: k<1024 interleaved (d=k>>1, ri=k&1) — layer-0 h-ring IS the input
//   both: k>=1024 interleaved h (d=(k-1024)>>1, ri)
__global__ void pack_weights_k(const float* __restrict__ Wi_r, const float* __restrict__ Wi_i,
                               const float* __restrict__ Wh_r, const float* __restrict__ Wh_i,
                               unsigned short* __restrict__ wp) {
  uint32_t idx = blockIdx.x * 256u + threadIdx.x;   // < 16,777,216
  int j    = idx & 7;
  int lane = (idx >> 3) & 63;
  int nt   = (idx >> 9) & 1;
  int kt   = (idx >> 10) & 63;
  int nb   = (idx >> 16) & 127;
  int l    = idx >> 23;
  int mrow = lane & 15, quad = lane >> 4;
  int n_col = nt * 16 + mrow;
  int dd = n_col >> 3, g = n_col & 7;
  int jrow = (g & 3) * 512 + nb * 4 + dd;       // row in the (4H,H) weight
  int k = kt * 32 + quad * 8 + j;
  bool im = (g >= 4);
  size_t ro = ((size_t)l * 2048 + jrow) * 512;
  float v;
  if (k < 1024 && l == 0) {                      // planar x segment
    int seg = k >> 9, kk = k & 511;
    if (seg == 0) v = im ? Wi_i[ro + kk] :  Wi_r[ro + kk];
    else          v = im ? Wi_r[ro + kk] : -Wi_i[ro + kk];
  } else {                                       // interleaved segment
    int kk = k & 1023;
    int d = kk >> 1, ri = kk & 1;
    const float* Wr = (k < 1024) ? Wi_r : Wh_r;
    const float* Wm = (k < 1024) ? Wi_i : Wh_i;
    if (ri == 0) v = im ? Wm[ro + d] :  Wr[ro + d];
    else         v = im ? Wr[ro + d] : -Wm[ro + d];
  }
  wp[idx] = f2bf(v);
}

// bias packed as [l][nb][n_col(32)] fp32 (n_col = dd*8+g)
__global__ void pack_bias_k(const float* __restrict__ bi_r, const float* __restrict__ bi_i,
                            const float* __restrict__ bh_r, const float* __restrict__ bh_i,
                            float* __restrict__ bp) {
  uint32_t idx = blockIdx.x * 256u + threadIdx.x;   // < 8192
  int n_col = idx & 31, nb = (idx >> 5) & 127, l = idx >> 12;
  int dd = n_col >> 3, g = n_col & 7;
  int j = (g & 3) * 512 + nb * 4 + dd;
  float v = (g >= 4) ? (bi_i[l * 2048 + j] + bh_i[l * 2048 + j])
                     : (bi_r[l * 2048 + j] + bh_r[l * 2048 + j]);
  bp[idx] = v;
}

__global__ void init_state_k(const float* __restrict__ h0_r, const float* __restrict__ h0_i,
                             uint32_t* __restrict__ hring32, uint32_t* __restrict__ flags) {
  uint32_t idx = blockIdx.x * 256u + threadIdx.x;   // < 65536 = L*B*H
  flags[idx] = 0;                                   // all 256x256 flag words
  int d = idx & 511, b = (idx >> 9) & 63, l = idx >> 15;
  // layer l first reads its own ring at phase p0=2l from slot (p0-1)&3
  int slot = (2 * l + 3) & 3;                       // l0 -> 3, l1 -> 1
  uint32_t* row = hring32 + (((size_t)l * 4 + slot) * 64 + b) * 512;
  row[d] = ((uint32_t)f2bf(h0_i[idx]) << 16) | (uint32_t)f2bf(h0_r[idx]);
}

__global__ void convert_x_k(const float* __restrict__ xr, const float* __restrict__ xi,
                            unsigned short* __restrict__ xbf) {
  uint32_t idx = blockIdx.x * 256u + threadIdx.x;   // < 33,554,432 = T*B*1024
  int k = idx & 1023;
  uint32_t row = idx >> 10;                         // t*64 + b
  float v = (k < 512) ? xr[(size_t)row * 512 + k] : xi[(size_t)row * 512 + (k - 512)];
  xbf[idx] = f2bf(v);
}

// ---------------- main persistent kernel ----------------

__global__ __launch_bounds__(256, 1) void lstm_persist_k(
    const float* __restrict__ xr, const float* __restrict__ xi,
    const float* __restrict__ c0_r, const float* __restrict__ c0_i,
    const unsigned short* __restrict__ wp, const float* __restrict__ bp,
    uint32_t* __restrict__ hring32, const unsigned short* __restrict__ xbf,
    float* __restrict__ out, uint32_t* flags, int use_xbf)
{
  __shared__ short8 Wb[8192];                  // 131,072 B : [kt][nt][lane] fragments
  __shared__ float Glds[64 * 33];              //   8,448 B
  __shared__ float bias_s[32];

  const int l   = blockIdx.x >> 7;     // layer
  const int nb  = blockIdx.x & 127;    // gate-col chunk [32nb, 32nb+32)
  const int bid = blockIdx.x;
  const int tid = threadIdx.x;

  // stage this block's weight slice into LDS: straight 131,072B contiguous copy
  {
    const short8* src = (const short8*)(wp + (((size_t)l * 128 + nb) << 16));
    #pragma unroll
    for (int i = 0; i < 32; ++i) Wb[i * 256 + tid] = src[i * 256 + tid];
    if (tid < 32) bias_s[tid] = bp[(l * 128 + nb) * 32 + tid];
  }

  // elementwise ownership: 4 consecutive lanes own the 4 dds of one batch
  // -> per-thread 4B h stores coalesce into 16B segments (R3 mapping).
  const int b_e = tid >> 2, dd_e = tid & 3;
  const int d_e = nb * 4 + dd_e;
  float cr = c0_r[(l * 64 + b_e) * 512 + d_e];
  float ci = c0_i[(l * 64 + b_e) * 512 + d_e];
  __syncthreads();

  // wave w = m-tile w: batches b = w*16 + mrow ; computes both n-tiles
  const int wv = tid >> 6, lane = tid & 63;
  const int quad = lane >> 4, mrow = lane & 15;
  const int bm = wv * 16 + mrow;                  // this lane's A row (batch)
  const bool cvt_path = (l == 0) && (!use_xbf);

  for (int p = 0; p < NPHASE; ++p) {
    const int t = p - 2 * l;                      // layer l at lag 2l
    const bool active = (t >= 0) && (t < 512);
    floatx4 acc0 = {0.f, 0.f, 0.f, 0.f}, acc1 = {0.f, 0.f, 0.f, 0.f};

    // ---- A: x-half GEMM (independent of the pending barrier) ----
    if (active) {
      if (l == 0) {
        if (cvt_path) {
          const size_t xtb = ((size_t)t * 64 + bm) * 512 + quad * 8;
          #pragma unroll 8
          for (int kt = 0; kt < 32; ++kt) {
            const float* xb = ((kt < 16) ? xr : xi) + xtb + (kt & 15) * 32;
            floatv4 f0 = *(const floatv4*)xb;
            floatv4 f1 = *(const floatv4*)(xb + 4);
            short8 a;
            #pragma unroll
            for (int jj = 0; jj < 4; ++jj) { a[jj] = (short)f2bf(f0[jj]); a[jj+4] = (short)f2bf(f1[jj]); }
            short8 bf0 = Wb[(kt * 2 + 0) * 64 + lane];
            short8 bf1 = Wb[(kt * 2 + 1) * 64 + lane];
            acc0 = __builtin_amdgcn_mfma_f32_16x16x32_bf16(a, bf0, acc0, 0, 0, 0);
            acc1 = __builtin_amdgcn_mfma_f32_16x16x32_bf16(a, bf1, acc1, 0, 0, 0);
          }
        } else {
          const unsigned short* xb = xbf + ((size_t)t * 64 + bm) * 1024 + quad * 8;
          #pragma unroll 8
          for (int kt = 0; kt < 32; ++kt) {
            short8 a = *(const short8*)(xb + kt * 32);
            short8 bf0 = Wb[(kt * 2 + 0) * 64 + lane];
            short8 bf1 = Wb[(kt * 2 + 1) * 64 + lane];
            acc0 = __builtin_amdgcn_mfma_f32_16x16x32_bf16(a, bf0, acc0, 0, 0, 0);
            acc1 = __builtin_amdgcn_mfma_f32_16x16x32_bf16(a, bf1, acc1, 0, 0, 0);
          }
        }
      } else {
        // layer-1 input = layer-0 h[t=p-2]: slot (p-2)&3, written at phase
        // p-2, visibility guaranteed by barrier gen p-1 (polled last iter).
        const uint32_t* xb = hring32 + (((size_t)0 * 4 + ((p - 2) & 3)) * 64 + bm) * 512 + quad * 4;
        uintx4 xp[32];
        #pragma unroll
        for (int i = 0; i < 32; ++i) xp[i] = ld_bypass_b128(xb + i * 16);
        wait_vm0();
        #pragma unroll
        for (int i = 0; i < 32; ++i) {
          short8 a = __builtin_bit_cast(short8, xp[i]);
          short8 bf0 = Wb[(i * 2 + 0) * 64 + lane];
          short8 bf1 = Wb[(i * 2 + 1) * 64 + lane];
          acc0 = __builtin_amdgcn_mfma_f32_16x16x32_bf16(a, bf0, acc0, 0, 0, 0);
          acc1 = __builtin_amdgcn_mfma_f32_16x16x32_bf16(a, bf1, acc1, 0, 0, 0);
        }
      }
    }

    // ---- B: fan-out barrier: poll OWN private 256-flag array until all >= p.
    // One 64-lane dwordx4 bypass load sweeps the whole 1KB array per RTT.
    {
      const uint32_t g = (uint32_t)p;
      if (wv == 0) {
        const uint32_t* fp = flags + (size_t)bid * 256 + lane * 4;
        long budget = (1L << 22);
        for (;;) {
          uintx4 v = ld_bypass_b128(fp);
          wait_vm0();
          bool ok = (v.x >= g) & (v.y >= g) & (v.z >= g) & (v.w >= g);
          if (__all(ok)) break;
          if (--budget <= 0) break;
        }
      }
      __syncthreads();   // releases waves 1-3; exec+compiler fence for C
      // NO cache fence: ring reads below bypass L1/L2 (sc0 sc1).
    }

    // ---- C: h-half GEMM (own layer state, slot (p-1)&3; written ph p-1) ----
    if (active) {
      const uint32_t* hb = hring32 + (((size_t)l * 4 + ((p - 1) & 3)) * 64 + bm) * 512 + quad * 4;
      uintx4 hp[32];
      #pragma unroll
      for (int i = 0; i < 32; ++i) hp[i] = ld_bypass_b128(hb + i * 16);
      wait_vm0();
      #pragma unroll
      for (int i = 0; i < 32; ++i) {
        short8 a = __builtin_bit_cast(short8, hp[i]);
        short8 bf0 = Wb[((32 + i) * 2 + 0) * 64 + lane];
        short8 bf1 = Wb[((32 + i) * 2 + 1) * 64 + lane];
        acc0 = __builtin_amdgcn_mfma_f32_16x16x32_bf16(a, bf0, acc0, 0, 0, 0);
        acc1 = __builtin_amdgcn_mfma_f32_16x16x32_bf16(a, bf1, acc1, 0, 0, 0);
      }
      // D layout: col = lane&15, row(within m-tile) = quad*4 + r  (m89/m91)
      const float bb0 = bias_s[mrow], bb1 = bias_s[16 + mrow];
      const int rowb = wv * 16 + quad * 4;
      #pragma unroll
      for (int r = 0; r < 4; ++r) {
        Glds[(rowb + r) * 33 + mrow]      = acc0[r] + bb0;
        Glds[(rowb + r) * 33 + 16 + mrow] = acc1[r] + bb1;
      }
    }
    __syncthreads();

    // ---- D: nonlinearity + write-through h store (coalesced 4-lane groups) --
    float h_r = 0.f, h_i = 0.f;
    if (active) {
      const float* gp = &Glds[b_e * 33 + dd_e * 8];
      float i_r = sigm(gp[0]), f_r = sigm(gp[1]), gc_r = tanhf_(gp[2]), o_r = sigm(gp[3]);
      float i_i = sigm(gp[4]), f_i = sigm(gp[5]), gc_i = tanhf_(gp[6]), o_i = sigm(gp[7]);
      float cr2 = f_r * cr - f_i * ci + i_r * gc_r - i_i * gc_i;
      float ci2 = f_r * ci + f_i * cr + i_r * gc_i + i_i * gc_r;
      cr = cr2; ci = ci2;
      float t_r = tanhf_(cr), t_i = tanhf_(ci);
      h_r = o_r * t_r - o_i * t_i;
      h_i = o_r * t_i + o_i * t_r;
      uint32_t hpk = ((uint32_t)f2bf(h_i) << 16) | (uint32_t)f2bf(h_r);
      uint32_t* hw = hring32 + (((size_t)l * 4 + (p & 3)) * 64 + b_e) * 512 + d_e;
      __hip_atomic_store(hw, hpk, __ATOMIC_RELAXED, __HIP_MEMORY_SCOPE_AGENT);
    }
    // __syncthreads: every wave waits vmcnt(0) first -> ALL h stores of this
    // block are acked at the coherence point before any flag store issues.
    __syncthreads();

    // ---- fan-out arrival: thread tid notifies consumer block tid ----
    __hip_atomic_store(&flags[(size_t)tid * 256 + bid], (uint32_t)(p + 1),
                       __ATOMIC_RELAXED, __HIP_MEMORY_SCOPE_AGENT);

    // ---- E: sequence/final outputs (plain cached; gate nothing -> after
    //        arrival, overlapping the next phase's x-half) ----
    if (active) {
      if (l == 1) {
        size_t o = ((size_t)t * 64 + b_e) * 512 + d_e;
        out[o]             = h_r;
        out[16777216u + o] = h_i;
      }
      if (t == 511) {
        size_t o = 33554432u + ((size_t)l * 64 + b_e) * 512 + d_e;
        out[o]          = h_r;
        out[o + 65536u] = h_i;
      }
    }
  }
}

// ---------------- host ----------------

extern "C" void kernel_launch(void* const* d_in, const int* in_sizes, int n_in,
                              void* d_out, int out_size, void* d_ws, size_t ws_size,
                              hipStream_t stream) {
  const float* seq_r = (const float*)d_in[0];
  const float* seq_i = (const float*)d_in[1];
  const float* h0_r  = (const float*)d_in[2];
  const float* h0_i  = (const float*)d_in[3];
  const float* c0_r  = (const float*)d_in[4];
  const float* c0_i  = (const float*)d_in[5];
  const float* Wi_r  = (const float*)d_in[6];
  const float* Wi_i  = (const float*)d_in[7];
  const float* Wh_r  = (const float*)d_in[8];
  const float* Wh_i  = (const float*)d_in[9];
  const float* bi_r  = (const float*)d_in[10];
  const float* bi_i  = (const float*)d_in[11];
  const float* bh_r  = (const float*)d_in[12];
  const float* bh_i  = (const float*)d_in[13];

  char* ws = (char*)d_ws;
  uint32_t* flags  = (uint32_t*)ws;                 // flags[256][256] u32 (256KB)
  unsigned short* wp   = (unsigned short*)(ws + OFF_W);
  float*          bias = (float*)(ws + OFF_BIAS);
  uint32_t*       hrg  = (uint32_t*)(ws + OFF_H);
  unsigned short* xbf  = (unsigned short*)(ws + OFF_XBF);
  const int use_xbf = (ws_size >= NEED_XBF) ? 1 : 0;

  pack_weights_k<<<65536, 256, 0, stream>>>(Wi_r, Wi_i, Wh_r, Wh_i, wp);
  pack_bias_k<<<32, 256, 0, stream>>>(bi_r, bi_i, bh_r, bh_i, bias);
  init_state_k<<<256, 256, 0, stream>>>(h0_r, h0_i, hrg, flags);
  if (use_xbf) convert_x_k<<<131072, 256, 0, stream>>>(seq_r, seq_i, xbf);

  lstm_persist_k<<<256, 256, 0, stream>>>(seq_r, seq_i, c0_r, c0_i, wp, bias,
                                          hrg, xbf, (float*)d_out, flags, use_xbf);
}